// Round 5
// baseline (201.784 us; speedup 1.0000x reference)
//
#include <hip/hip_runtime.h>

// H=16, DK=DV=64, D=1024, N=M=2048.
// scores[h,n,m] = ((A_h^T q_n + vh_h) . k_m)/8 + row-consts (drop in softmax),
//   A_h[i][j] = sum_d Wq[h,i,d]*Wk[h,j,d],  vh_h[j] = sum_d Wk[h,j,d]*bq[h,d].
// pooled[d] = sum_h sum_v r_h[v]*Wv[h,v,d] + 2048*sum_h bv[h,d],
//   r_h[v] = sum_n softmax_row . V[:,v].   out = pooled @ Wo^T + bo.
// No max-tracking softmax: |s|max ~ 27 << 88 -> exp safe in fp32.
//
// v5 = v3 pipeline + REAL K/V prefetch in flash (resubmit: round-4 bench was
// an infra failure, kernel never ran; vmcnt ledger + bounds re-audited clean):
//  - asm global_load_dwordx4 batches (8 at a time), counted s_waitcnt vmcnt(N)
//  - the waitcnt asm takes the 8 destination vectors as "+v" operands, so all
//    consumers/copies have a hard SSA dependency on the wait (v4's NaN was
//    copies reading asm-load destinations before the wait; sched_barrier
//    doesn't order pure-register consumers).
//  - exp fused into the QK cm-loop (S lives 8 regs, not 32) -> peak live
//    ~146 VGPR < 168 cap of __launch_bounds__(256,3): no loop spills
//    (loop spills would desync vmcnt counting).

typedef __attribute__((ext_vector_type(4))) float floatx4;
typedef __attribute__((ext_vector_type(8))) short shortx8;

__device__ inline unsigned short f2bf(float f) {
    unsigned int u = __float_as_uint(f);
    u += 0x7FFFu + ((u >> 16) & 1u);   // RNE
    return (unsigned short)(u >> 16);
}
__device__ inline float bf2f(unsigned short s) {
    return __uint_as_float(((unsigned int)s) << 16);
}

// pinned global load (issue only; completion is tracked by vmcnt)
#define GLOAD(dst, p) \
    asm volatile("global_load_dwordx4 %0, %1, off" : "=&v"(dst) : "v"(p))
// counted wait that DEFINES the 8 loaded vectors: consumers depend on it.
#define TIEDWAIT(cnt, a) \
    asm volatile("s_waitcnt vmcnt(" #cnt ")" \
        : "+v"(a[0]), "+v"(a[1]), "+v"(a[2]), "+v"(a[3]), \
          "+v"(a[4]), "+v"(a[5]), "+v"(a[6]), "+v"(a[7]) :: "memory")

// =================== prep: fused A-partials / K-cvt / V-transpose ============
// grid 176: blocks 0-127: (g,h) A-partial + vh-partial via MFMA (k-chunk 128)
//           blocks 128-143: K bf16 convert + r zero
//           blocks 144-175: V transpose -> VT bf16
__global__ __launch_bounds__(256) void prep_kernel(
    const float* __restrict__ Wq, const float* __restrict__ Wk,
    const float* __restrict__ bq, const float* __restrict__ keys,
    const float* __restrict__ values,
    float* __restrict__ Apart, float* __restrict__ vhpart,
    unsigned short* __restrict__ Kb, unsigned short* __restrict__ VT,
    float* __restrict__ r_ws) {
    const int tid = threadIdx.x;
    const int bx = blockIdx.x;
    __shared__ __align__(16) unsigned char sm[36352];
    if (bx < 128) {
        const int g = bx >> 4, h = bx & 15;
        const int c0 = g * 128;
        unsigned short* wq = (unsigned short*)sm;            // 64*136 ushort
        unsigned short* wk = (unsigned short*)(sm + 17408);  // 64*136 ushort
        float* bqs = (float*)(sm + 34816);                   // 128
        float* vred = (float*)(sm + 35328);                  // 4*64
        {
            int row = tid >> 2, cs = (tid & 3) * 32;
            const float* wqp = Wq + (size_t)(h * 64 + row) * 1024 + c0 + cs;
            const float* wkp = Wk + (size_t)(h * 64 + row) * 1024 + c0 + cs;
            #pragma unroll
            for (int u = 0; u < 8; ++u) {
                float4 a = *(const float4*)&wqp[u * 4];
                float4 b = *(const float4*)&wkp[u * 4];
                *(ushort4*)&wq[row * 136 + cs + u * 4] =
                    (ushort4){f2bf(a.x), f2bf(a.y), f2bf(a.z), f2bf(a.w)};
                *(ushort4*)&wk[row * 136 + cs + u * 4] =
                    (ushort4){f2bf(b.x), f2bf(b.y), f2bf(b.z), f2bf(b.w)};
            }
            if (tid < 128) bqs[tid] = bq[h * 1024 + c0 + tid];
        }
        __syncthreads();
        const int w = tid >> 6, lane = tid & 63;
        const int ln = lane & 15, quad = lane >> 4;
        {   // vh partial
            const int j = tid & 63, half = tid >> 6;
            float accv = 0.f;
            #pragma unroll
            for (int u = 0; u < 32; ++u)
                accv += bf2f(wk[j * 136 + half * 32 + u]) * bqs[half * 32 + u];
            vred[half * 64 + j] = accv;
        }
        // A-tile: wave w -> rows w*16..+15
        shortx8 af[4];
        #pragma unroll
        for (int kk = 0; kk < 4; ++kk)
            af[kk] = *(shortx8*)&wq[(w * 16 + ln) * 136 + kk * 32 + quad * 8];
        float* ap = Apart + (size_t)bx * 4096;
        #pragma unroll
        for (int cn = 0; cn < 4; ++cn) {
            floatx4 acc = {};
            #pragma unroll
            for (int kk = 0; kk < 4; ++kk) {
                shortx8 bf_ = *(shortx8*)&wk[(cn * 16 + ln) * 136 + kk * 32 + quad * 8];
                acc = __builtin_amdgcn_mfma_f32_16x16x32_bf16(af[kk], bf_, acc, 0, 0, 0);
            }
            #pragma unroll
            for (int r = 0; r < 4; ++r)
                ap[(w * 16 + quad * 4 + r) * 64 + cn * 16 + ln] = acc[r];
        }
        __syncthreads();
        if (tid < 64)
            vhpart[bx * 64 + tid] = vred[tid] + vred[64 + tid] +
                                    vred[128 + tid] + vred[192 + tid];
    } else if (bx < 144) {
        int bk = bx - 128;
        int base = (bk * 256 + tid) * 32;
        #pragma unroll
        for (int u = 0; u < 8; ++u) {
            float4 a = *(const float4*)&keys[base + u * 4];
            *(ushort4*)&Kb[base + u * 4] =
                (ushort4){f2bf(a.x), f2bf(a.y), f2bf(a.z), f2bf(a.w)};
        }
        if (tid < 64) r_ws[bk * 64 + tid] = 0.f;
    } else {
        int bb = bx - 144, m0 = bb * 64;
        unsigned short* vts = (unsigned short*)sm;   // 64*72 ushort
        #pragma unroll
        for (int it = 0; it < 4; ++it) {
            int gi = tid + it * 256;
            int m = gi >> 4, c4 = (gi & 15) * 4;
            float4 a = *(const float4*)&values[(size_t)(m0 + m) * 64 + c4];
            vts[(c4 + 0) * 72 + m] = f2bf(a.x);
            vts[(c4 + 1) * 72 + m] = f2bf(a.y);
            vts[(c4 + 2) * 72 + m] = f2bf(a.z);
            vts[(c4 + 3) * 72 + m] = f2bf(a.w);
        }
        __syncthreads();
        #pragma unroll
        for (int it = 0; it < 2; ++it) {
            int gi = tid + it * 256;
            int v = gi >> 3, seg = (gi & 7) * 8;
            *(shortx8*)&VT[v * 2048 + m0 + seg] = *(shortx8*)&vts[v * 72 + seg];
        }
    }
}

// =================== reduceA: sum 8 A-partials -> Atlg (A^T, bf16), vhg ======
__global__ __launch_bounds__(256) void reduceA_kernel(
    const float* __restrict__ Apart, const float* __restrict__ vhpart,
    unsigned short* __restrict__ Atlg, float* __restrict__ vhg) {
    const int tid = threadIdx.x;
    const int h = blockIdx.x >> 2, uq = blockIdx.x & 3;
    #pragma unroll
    for (int uu = 0; uu < 4; ++uu) {
        int e = (uq * 4 + uu) * 256 + tid;     // e = i*64 + j
        float s = 0.f;
        #pragma unroll
        for (int g = 0; g < 8; ++g)
            s += Apart[g * 65536 + h * 4096 + e];
        Atlg[h * 4096 + (e & 63) * 64 + (e >> 6)] = f2bf(s);   // A^T[j][i]
    }
    if (uq == 0 && tid < 64) {
        float s = 0.f;
        #pragma unroll
        for (int g = 0; g < 8; ++g) s += vhpart[(g * 16 + h) * 64 + tid];
        vhg[h * 64 + tid] = s;
    }
}

// =================== flash v5: grid (64 qtiles of 32 rows, 16 h) =============
// 4 waves: wave w -> ALL 32 rows (2 MFMA row-tiles), key chunk w (512 keys,
// 8 steps of 64, stagger-rotated). K/V frags via pinned asm loads with
// tied-operand counted vmcnt waits. ZERO barriers in the loop.
#define QSCALE 0.18033688f   /* 0.125 * log2(e) */
__global__ __launch_bounds__(256, 3) void flash_kernel(
    const float* __restrict__ queries, const unsigned short* __restrict__ Atlg,
    const float* __restrict__ vhg, const unsigned short* __restrict__ Kb,
    const unsigned short* __restrict__ VT, float* __restrict__ r_ws) {
    const int h = blockIdx.y;
    const int n0 = blockIdx.x * 32;
    const int tid = threadIdx.x;
    const int w = tid >> 6, lane = tid & 63;
    const int ln = lane & 15, quad = lane >> 4;
    const int cw = w;                    // key chunk: keys cw*512 .. +512

    __shared__ __align__(16) unsigned char lds[24064];
    __shared__ float vhs[64];
    // phase A/B: qstage @0 (4608B), Atl @4608 (9216B)
    // main loop: Pw @ w*4864 (32*76*2 each, ends 19456); qh @19456 (4608)
    // epilogue:  LSUM @0 (128 f32), LINV @512 (32 f32), Rred @640 (256 f32)
    unsigned short* qstage = (unsigned short*)lds;
    unsigned short* Atl = (unsigned short*)(lds + 4608);
    unsigned short* qh  = (unsigned short*)(lds + 19456);
    unsigned short* Pw  = (unsigned short*)(lds + w * 4864);
    float* LSUM = (float*)lds;
    float* LINV = (float*)(lds + 512);
    float* Rred = (float*)(lds + 640);

    // ---- phase A: stage queries (bf16), load Atl (8KB coalesced), vhs ------
    {
        int row = tid >> 3, c8 = (tid & 7) * 8;
        const float* qp = queries + (size_t)(n0 + row) * 64 + c8;
        float4 a = *(const float4*)qp;
        float4 b = *(const float4*)(qp + 4);
        *(ushort4*)&qstage[row * 72 + c8] =
            (ushort4){f2bf(a.x), f2bf(a.y), f2bf(a.z), f2bf(a.w)};
        *(ushort4*)&qstage[row * 72 + c8 + 4] =
            (ushort4){f2bf(b.x), f2bf(b.y), f2bf(b.z), f2bf(b.w)};
    }
    #pragma unroll
    for (int k = 0; k < 2; ++k) {
        int seg = tid * 2 + k, row = seg >> 3, off = (seg & 7) * 8;
        *(shortx8*)&Atl[row * 72 + off] =
            *(const shortx8*)&Atlg[h * 4096 + row * 64 + off];
    }
    if (tid < 64) vhs[tid] = vhg[h * 64 + tid];
    __syncthreads();

    // ---- phase B: qhat via MFMA; wave w -> tile (w&1), cn pair (w>>1) ------
    {
        const int t = w & 1, cnb = (w >> 1) * 2;
        shortx8 qa[2];
        #pragma unroll
        for (int kk = 0; kk < 2; ++kk)
            qa[kk] = *(shortx8*)&qstage[(t * 16 + ln) * 72 + kk * 32 + quad * 8];
        #pragma unroll
        for (int i = 0; i < 2; ++i) {
            int cn = cnb + i;
            floatx4 acc = {};
            #pragma unroll
            for (int kk = 0; kk < 2; ++kk) {
                shortx8 bfr = *(shortx8*)&Atl[(cn * 16 + ln) * 72 + kk * 32 + quad * 8];
                acc = __builtin_amdgcn_mfma_f32_16x16x32_bf16(qa[kk], bfr, acc, 0, 0, 0);
            }
            #pragma unroll
            for (int r = 0; r < 4; ++r)
                qh[(t * 16 + quad * 4 + r) * 72 + cn * 16 + ln] =
                    f2bf((acc[r] + vhs[cn * 16 + ln]) * QSCALE);
        }
    }
    __syncthreads();

    // ---- main loop: 8 steps of 64 keys, pinned prefetch, no barriers -------
    shortx8 qf[2][2];
    #pragma unroll
    for (int t = 0; t < 2; ++t)
        #pragma unroll
        for (int kk = 0; kk < 2; ++kk)
            qf[t][kk] = *(shortx8*)&qh[(t * 16 + ln) * 72 + kk * 32 + quad * 8];

    const unsigned short* KbC = Kb + (size_t)(cw * 512) * 64;
    const unsigned short* VTC = VT + cw * 512;
    const int boff = (blockIdx.x * 3 + h) & 7;   // L2 set stagger

    shortx8 pk[8], pv[8];
    {   // prologue: issue K(s0) then V(s0)  -> 16 outstanding
        const int s0 = boff;
        #pragma unroll
        for (int j = 0; j < 8; ++j)
            GLOAD(pk[j], KbC + ((size_t)(s0 * 64 + (j >> 1) * 16 + ln) * 64 +
                                (j & 1) * 32 + quad * 8));
        #pragma unroll
        for (int j = 0; j < 8; ++j)
            GLOAD(pv[j], VTC + ((size_t)((j >> 1) * 16 + ln) * 2048 + s0 * 64 +
                                (j & 1) * 32 + quad * 8));
    }

    floatx4 O0[4] = {}, O1[4] = {};
    float lacc0[4] = {}, lacc1[4] = {};

    #pragma unroll
    for (int i = 0; i < 8; ++i) {
        const int sn = (i + 1 + boff) & 7;
        TIEDWAIT(8, pk);                 // K(s) landed (V(s) still in flight)
        // QK fused with exp: S lives one cm (8 regs) at a time
        #pragma unroll
        for (int cm = 0; cm < 4; ++cm) {
            floatx4 a0 = {}, a1 = {};
            a0 = __builtin_amdgcn_mfma_f32_16x16x32_bf16(qf[0][0], pk[cm * 2], a0, 0, 0, 0);
            a0 = __builtin_amdgcn_mfma_f32_16x16x32_bf16(qf[0][1], pk[cm * 2 + 1], a0, 0, 0, 0);
            a1 = __builtin_amdgcn_mfma_f32_16x16x32_bf16(qf[1][0], pk[cm * 2], a1, 0, 0, 0);
            a1 = __builtin_amdgcn_mfma_f32_16x16x32_bf16(qf[1][1], pk[cm * 2 + 1], a1, 0, 0, 0);
            if (cm == 3 && i < 7) {      // pk[0..5] dead: issue K(s+1)
                #pragma unroll
                for (int j = 0; j < 8; ++j)
                    GLOAD(pk[j], KbC + ((size_t)(sn * 64 + (j >> 1) * 16 + ln) * 64 +
                                        (j & 1) * 32 + quad * 8));
            }
            #pragma unroll
            for (int r = 0; r < 4; ++r) {
                float p0 = __builtin_amdgcn_exp2f(a0[r]); lacc0[r] += p0;
                Pw[(quad * 4 + r) * 76 + cm * 16 + ln] = f2bf(p0);
                float p1 = __builtin_amdgcn_exp2f(a1[r]); lacc1[r] += p1;
                Pw[(16 + quad * 4 + r) * 76 + cm * 16 + ln] = f2bf(p1);
            }
        }
        // P frags (same wave wrote them: lgkmcnt ordering only, no barrier)
        shortx8 pf[2][2];
        #pragma unroll
        for (int t = 0; t < 2; ++t)
            #pragma unroll
            for (int kk = 0; kk < 2; ++kk)
                pf[t][kk] = *(shortx8*)&Pw[(t * 16 + ln) * 76 + kk * 32 + quad * 8];
        if (i < 7) { TIEDWAIT(8, pv); } else { TIEDWAIT(0, pv); }  // V(s) landed
        // PV
        #pragma unroll
        for (int cv = 0; cv < 4; ++cv) {
            O0[cv] = __builtin_amdgcn_mfma_f32_16x16x32_bf16(pf[0][0], pv[cv * 2], O0[cv], 0, 0, 0);
            O0[cv] = __builtin_amdgcn_mfma_f32_16x16x32_bf16(pf[0][1], pv[cv * 2 + 1], O0[cv], 0, 0, 0);
            O1[cv] = __builtin_amdgcn_mfma_f32_16x16x32_bf16(pf[1][0], pv[cv * 2], O1[cv], 0, 0, 0);
            O1[cv] = __builtin_amdgcn_mfma_f32_16x16x32_bf16(pf[1][1], pv[cv * 2 + 1], O1[cv], 0, 0, 0);
        }
        if (i < 7) {                    // issue V(s+1)
            #pragma unroll
            for (int j = 0; j < 8; ++j)
                GLOAD(pv[j], VTC + ((size_t)((j >> 1) * 16 + ln) * 2048 + sn * 64 +
                                    (j & 1) * 32 + quad * 8));
        }
    }

    // ---- epilogue: row-sums, LINV, per-lane O.LINV dot, quad-reduce --------
    float lr0[4], lr1[4];
    #pragma unroll
    for (int r = 0; r < 4; ++r) {
        float x0 = lacc0[r], x1 = lacc1[r];
        #pragma unroll
        for (int o = 1; o <= 8; o <<= 1) { x0 += __shfl_xor(x0, o); x1 += __shfl_xor(x1, o); }
        lr0[r] = x0; lr1[r] = x1;
    }
    __syncthreads();   // all waves done with Pw/qh -> overlay LSUM/LINV/Rred
    if (ln == 0) {
        #pragma unroll
        for (int r = 0; r < 4; ++r) {
            LSUM[w * 32 + quad * 4 + r] = lr0[r];
            LSUM[w * 32 + 16 + quad * 4 + r] = lr1[r];
        }
    }
    __syncthreads();
    if (tid < 32)
        LINV[tid] = 1.0f / (LSUM[tid] + LSUM[32 + tid] + LSUM[64 + tid] + LSUM[96 + tid]);
    __syncthreads();
    {
        float sacc[4];
        #pragma unroll
        for (int cv = 0; cv < 4; ++cv) {
            float s = 0.f;
            #pragma unroll
            for (int r = 0; r < 4; ++r) {
                s += O0[cv][r] * LINV[quad * 4 + r];
                s += O1[cv][r] * LINV[16 + quad * 4 + r];
            }
            s += __shfl_xor(s, 16);
            s += __shfl_xor(s, 32);
            sacc[cv] = s;
        }
        if (quad == 0) {
            #pragma unroll
            for (int cv = 0; cv < 4; ++cv)
                Rred[w * 64 + cv * 16 + ln] = sacc[cv];
        }
    }
    __syncthreads();
    if (tid < 64)
        atomicAdd(&r_ws[h * 64 + tid],
                  Rred[tid] + Rred[64 + tid] + Rred[128 + tid] + Rred[192 + tid]);
}

// =================== pool: pooled[d] = 2048*sum_h bv + sum_hv r*Wv ----------
__global__ __launch_bounds__(256) void pool_kernel(
    const float* __restrict__ Wv, const float* __restrict__ bv,
    const float* __restrict__ r_ws, float* __restrict__ pooled) {
    const int tid = threadIdx.x;
    const int d0 = blockIdx.x * 16;       // grid 64
    const int d = tid & 15, hh = tid >> 4;
    __shared__ float red[16][17];
    float acc = bv[hh * 1024 + d0 + d] * 2048.0f;
    const float* rv = r_ws + hh * 64;
    const float* wp = Wv + (size_t)hh * 64 * 1024 + d0 + d;
    #pragma unroll 8
    for (int v = 0; v < 64; ++v) acc += rv[v] * wp[(size_t)v * 1024];
    red[hh][d] = acc;
    __syncthreads();
    if (tid < 16) {
        float s = 0.f;
        #pragma unroll
        for (int g = 0; g < 16; ++g) s += red[g][tid];
        pooled[d0 + tid] = s;
    }
}

// =================== out: out[dp] = pooled . Wo[dp,:] + bo[dp] ---------------
__global__ __launch_bounds__(256) void out_kernel(
    const float* __restrict__ Wo, const float* __restrict__ bo,
    const float* __restrict__ pooled, float* __restrict__ out) {
    const int tid = threadIdx.x, w = tid >> 6, lane = tid & 63;
    const int dp = blockIdx.x * 4 + w;    // grid 256
    const float* wr = Wo + (size_t)dp * 1024 + lane * 16;
    const float* pp = pooled + lane * 16;
    float acc = 0.f;
    #pragma unroll
    for (int u = 0; u < 4; ++u) {
        float4 a = *(const float4*)&wr[u * 4];
        float4 p = *(const float4*)&pp[u * 4];
        acc += a.x * p.x + a.y * p.y + a.z * p.z + a.w * p.w;
    }
    #pragma unroll
    for (int o = 32; o > 0; o >>= 1) acc += __shfl_xor(acc, o);
    if (lane == 0) out[dp] = acc + bo[dp];
}

extern "C" void kernel_launch(void* const* d_in, const int* in_sizes, int n_in,
                              void* d_out, int out_size, void* d_ws, size_t ws_size,
                              hipStream_t stream) {
    const float* queries = (const float*)d_in[0];
    const float* keys    = (const float*)d_in[1];
    const float* values  = (const float*)d_in[2];
    const float* Wq      = (const float*)d_in[3];
    const float* bq      = (const float*)d_in[4];
    const float* Wk      = (const float*)d_in[5];
    // d_in[6] = bk: row-constant under softmax, unused
    const float* Wv      = (const float*)d_in[7];
    const float* bv      = (const float*)d_in[8];
    const float* Wo      = (const float*)d_in[9];
    const float* bo      = (const float*)d_in[10];
    float* out = (float*)d_out;

    float* Apart  = (float*)d_ws;                 // 128*4096 floats
    float* vhpart = Apart + 524288;               // 128*64
    float* r_ws   = vhpart + 8192;                // 1024
    float* pooled = r_ws + 1024;                  // 1024
    unsigned short* Kb = (unsigned short*)(pooled + 1024);  // 2048*64
    unsigned short* VT = Kb + 131072;                       // 64*2048
    unsigned short* Atlg = VT + 131072;                     // 16*64*64 bf16
    float* vhg = (float*)(Atlg + 65536);                    // 16*64
    // total ws: ~2.8 MB

    prep_kernel<<<176, 256, 0, stream>>>(Wq, Wk, bq, keys, values,
                                         Apart, vhpart, Kb, VT, r_ws);
    reduceA_kernel<<<64, 256, 0, stream>>>(Apart, vhpart, Atlg, vhg);
    flash_kernel<<<dim3(64, 16), 256, 0, stream>>>(queries, Atlg, vhg,
                                                   Kb, VT, r_ws);
    pool_kernel<<<64, 256, 0, stream>>>(Wv, bv, r_ws, pooled);
    out_kernel<<<256, 256, 0, stream>>>(Wo, bo, pooled, out);
}

// Round 6
// 133.616 us; speedup vs baseline: 1.5102x; 1.5102x over previous
//
#include <hip/hip_runtime.h>

// H=16, DK=DV=64, D=1024, N=M=2048.
// scores[h,n,m] = ((A_h^T q_n + vh_h) . k_m)/8 + row-consts (drop in softmax),
//   A_h[i][j] = sum_d Wq[h,i,d]*Wk[h,j,d],  vh_h[j] = sum_d Wk[h,j,d]*bq[h,d].
// pooled[d] = sum_h sum_v r_h[v]*Wv[h,v,d] + 2048*sum_h bv[h,d],
//   r_h[v] = sum_n softmax_row . V[:,v].   out = pooled @ Wo^T + bo.
// No max-tracking softmax: |s|max ~ 27 << 88 -> exp safe in fp32.
//
// v6 = v3 + fragment-coalesced K/V layout (NO inline asm):
//  prep permutes K and V^T into MFMA-fragment order:
//    KbS[b][cm][kk][lane][8]  (b = key-block of 64, lane = quad*16+ln)
//    VTS[b][cv][hf][lane][8]
//  so each fragment load in flash is base + lane*16B (fully coalesced, 8
//  contiguous 128B lines vs 16 scattered 64B segments before) and all 8
//  loads of a step share ONE base with immediate offsets j*1024B.
//  v5's asm-tied prefetch is dead: it demoted pk/pv to scratch
//  (WRITE_SIZE 0.5->158MB, VGPR 84). Plain C + cheap addresses instead.

typedef __attribute__((ext_vector_type(4))) float floatx4;
typedef __attribute__((ext_vector_type(8))) short shortx8;

__device__ inline unsigned short f2bf(float f) {
    unsigned int u = __float_as_uint(f);
    u += 0x7FFFu + ((u >> 16) & 1u);   // RNE
    return (unsigned short)(u >> 16);
}
__device__ inline float bf2f(unsigned short s) {
    return __uint_as_float(((unsigned int)s) << 16);
}

// =================== prep: fused A-partials / K-perm / V-perm ================
// grid 176: blocks 0-127: (g,h) A-partial + vh-partial via MFMA (k-chunk 128)
//           blocks 128-143: K bf16 convert -> fragment order + r zero
//           blocks 144-175: V transpose -> fragment order
__global__ __launch_bounds__(256) void prep_kernel(
    const float* __restrict__ Wq, const float* __restrict__ Wk,
    const float* __restrict__ bq, const float* __restrict__ keys,
    const float* __restrict__ values,
    float* __restrict__ Apart, float* __restrict__ vhpart,
    unsigned short* __restrict__ KbS, unsigned short* __restrict__ VTS,
    float* __restrict__ r_ws) {
    const int tid = threadIdx.x;
    const int bx = blockIdx.x;
    __shared__ __align__(16) unsigned char sm[36352];
    if (bx < 128) {
        const int g = bx >> 4, h = bx & 15;
        const int c0 = g * 128;
        unsigned short* wq = (unsigned short*)sm;            // 64*136 ushort
        unsigned short* wk = (unsigned short*)(sm + 17408);  // 64*136 ushort
        float* bqs = (float*)(sm + 34816);                   // 128
        float* vred = (float*)(sm + 35328);                  // 4*64
        {
            int row = tid >> 2, cs = (tid & 3) * 32;
            const float* wqp = Wq + (size_t)(h * 64 + row) * 1024 + c0 + cs;
            const float* wkp = Wk + (size_t)(h * 64 + row) * 1024 + c0 + cs;
            #pragma unroll
            for (int u = 0; u < 8; ++u) {
                float4 a = *(const float4*)&wqp[u * 4];
                float4 b = *(const float4*)&wkp[u * 4];
                *(ushort4*)&wq[row * 136 + cs + u * 4] =
                    (ushort4){f2bf(a.x), f2bf(a.y), f2bf(a.z), f2bf(a.w)};
                *(ushort4*)&wk[row * 136 + cs + u * 4] =
                    (ushort4){f2bf(b.x), f2bf(b.y), f2bf(b.z), f2bf(b.w)};
            }
            if (tid < 128) bqs[tid] = bq[h * 1024 + c0 + tid];
        }
        __syncthreads();
        const int w = tid >> 6, lane = tid & 63;
        const int ln = lane & 15, quad = lane >> 4;
        {   // vh partial
            const int j = tid & 63, half = tid >> 6;
            float accv = 0.f;
            #pragma unroll
            for (int u = 0; u < 32; ++u)
                accv += bf2f(wk[j * 136 + half * 32 + u]) * bqs[half * 32 + u];
            vred[half * 64 + j] = accv;
        }
        // A-tile: wave w -> rows w*16..+15
        shortx8 af[4];
        #pragma unroll
        for (int kk = 0; kk < 4; ++kk)
            af[kk] = *(shortx8*)&wq[(w * 16 + ln) * 136 + kk * 32 + quad * 8];
        float* ap = Apart + (size_t)bx * 4096;
        #pragma unroll
        for (int cn = 0; cn < 4; ++cn) {
            floatx4 acc = {};
            #pragma unroll
            for (int kk = 0; kk < 4; ++kk) {
                shortx8 bf_ = *(shortx8*)&wk[(cn * 16 + ln) * 136 + kk * 32 + quad * 8];
                acc = __builtin_amdgcn_mfma_f32_16x16x32_bf16(af[kk], bf_, acc, 0, 0, 0);
            }
            #pragma unroll
            for (int r = 0; r < 4; ++r)
                ap[(w * 16 + quad * 4 + r) * 64 + cn * 16 + ln] = acc[r];
        }
        __syncthreads();
        if (tid < 64)
            vhpart[bx * 64 + tid] = vred[tid] + vred[64 + tid] +
                                    vred[128 + tid] + vred[192 + tid];
    } else if (bx < 144) {
        // K convert + permute: row m, half hf -> KbS[((b*4+cm)*2+hf)*512 +
        //   (quad*16+ln)*8 + e] = bf16(keys[m][hf*32+quad*8+e])
        int bk = bx - 128;
        int m = bk * 128 + (tid >> 1), hf = tid & 1;
        int b = m >> 6, cm = (m >> 4) & 3, ln = m & 15;
        const float* kp = keys + (size_t)m * 64 + hf * 32;
        unsigned short* dst = KbS + ((size_t)((b * 4 + cm) * 2 + hf) * 512 + ln * 8);
        #pragma unroll
        for (int q0 = 0; q0 < 4; ++q0) {
            float4 a = *(const float4*)&kp[q0 * 8];
            float4 c = *(const float4*)&kp[q0 * 8 + 4];
            *(ushort4*)&dst[q0 * 128] =
                (ushort4){f2bf(a.x), f2bf(a.y), f2bf(a.z), f2bf(a.w)};
            *(ushort4*)&dst[q0 * 128 + 4] =
                (ushort4){f2bf(c.x), f2bf(c.y), f2bf(c.z), f2bf(c.w)};
        }
        if (tid < 64) r_ws[bk * 64 + tid] = 0.f;
    } else {
        // V transpose + permute: VTS[((b*4+cv)*2+hf)*512 + (quad*16+ln)*8 + e]
        //   = bf16(values[b*64 + hf*32+quad*8+e][cv*16+ln])
        int bb = bx - 144, m0 = bb * 64;
        unsigned short* vts = (unsigned short*)sm;   // 64*72 ushort
        #pragma unroll
        for (int it = 0; it < 4; ++it) {
            int gi = tid + it * 256;
            int m = gi >> 4, c4 = (gi & 15) * 4;
            float4 a = *(const float4*)&values[(size_t)(m0 + m) * 64 + c4];
            vts[(c4 + 0) * 72 + m] = f2bf(a.x);
            vts[(c4 + 1) * 72 + m] = f2bf(a.y);
            vts[(c4 + 2) * 72 + m] = f2bf(a.z);
            vts[(c4 + 3) * 72 + m] = f2bf(a.w);
        }
        __syncthreads();
        #pragma unroll
        for (int it = 0; it < 2; ++it) {
            int gi = tid + it * 256;
            int v = gi >> 3, hf = (gi >> 2) & 1, quad = gi & 3;
            *(shortx8*)&VTS[(size_t)((bb * 4 + (v >> 4)) * 2 + hf) * 512 +
                            (quad * 16 + (v & 15)) * 8] =
                *(shortx8*)&vts[v * 72 + hf * 32 + quad * 8];
        }
    }
}

// =================== reduceA: sum 8 A-partials -> Atlg (A^T, bf16), vhg ======
__global__ __launch_bounds__(256) void reduceA_kernel(
    const float* __restrict__ Apart, const float* __restrict__ vhpart,
    unsigned short* __restrict__ Atlg, float* __restrict__ vhg) {
    const int tid = threadIdx.x;
    const int h = blockIdx.x >> 2, uq = blockIdx.x & 3;
    #pragma unroll
    for (int uu = 0; uu < 4; ++uu) {
        int e = (uq * 4 + uu) * 256 + tid;     // e = i*64 + j
        float s = 0.f;
        #pragma unroll
        for (int g = 0; g < 8; ++g)
            s += Apart[g * 65536 + h * 4096 + e];
        Atlg[h * 4096 + (e & 63) * 64 + (e >> 6)] = f2bf(s);   // A^T[j][i]
    }
    if (uq == 0 && tid < 64) {
        float s = 0.f;
        #pragma unroll
        for (int g = 0; g < 8; ++g) s += vhpart[(g * 16 + h) * 64 + tid];
        vhg[h * 64 + tid] = s;
    }
}

// =================== flash v6: grid (64 qtiles of 32 rows, 16 h) =============
// 4 waves: wave w -> ALL 32 rows (2 MFMA row-tiles), key chunk w (512 keys,
// 8 steps of 64). K/V frags from global in FRAGMENT-COALESCED layout:
// one base per step, 8 loads at base + lane*16B + j*1024B. No barriers.
#define QSCALE 0.18033688f   /* 0.125 * log2(e) */
__global__ __launch_bounds__(256, 3) void flash_kernel(
    const float* __restrict__ queries, const unsigned short* __restrict__ Atlg,
    const float* __restrict__ vhg, const unsigned short* __restrict__ KbS,
    const unsigned short* __restrict__ VTS, float* __restrict__ r_ws) {
    const int h = blockIdx.y;
    const int n0 = blockIdx.x * 32;
    const int tid = threadIdx.x;
    const int w = tid >> 6, lane = tid & 63;
    const int ln = lane & 15, quad = lane >> 4;
    const int cw = w;                    // key chunk: keys cw*512 .. +512

    __shared__ __align__(16) unsigned char lds[24064];
    __shared__ float vhs[64];
    // phase A/B: qstage @0 (4608B), Atl @4608 (9216B)
    // main loop: Pw @ w*4864 (32*76*2 each, ends 19456); qh @19456 (4608)
    // epilogue:  LSUM @0 (128 f32), LINV @512 (32 f32), Rred @640 (256 f32)
    unsigned short* qstage = (unsigned short*)lds;
    unsigned short* Atl = (unsigned short*)(lds + 4608);
    unsigned short* qh  = (unsigned short*)(lds + 19456);
    unsigned short* Pw  = (unsigned short*)(lds + w * 4864);
    float* LSUM = (float*)lds;
    float* LINV = (float*)(lds + 512);
    float* Rred = (float*)(lds + 640);

    // ---- phase A: stage queries (bf16), load Atl (8KB coalesced), vhs ------
    {
        int row = tid >> 3, c8 = (tid & 7) * 8;
        const float* qp = queries + (size_t)(n0 + row) * 64 + c8;
        float4 a = *(const float4*)qp;
        float4 b = *(const float4*)(qp + 4);
        *(ushort4*)&qstage[row * 72 + c8] =
            (ushort4){f2bf(a.x), f2bf(a.y), f2bf(a.z), f2bf(a.w)};
        *(ushort4*)&qstage[row * 72 + c8 + 4] =
            (ushort4){f2bf(b.x), f2bf(b.y), f2bf(b.z), f2bf(b.w)};
    }
    #pragma unroll
    for (int k = 0; k < 2; ++k) {
        int seg = tid * 2 + k, row = seg >> 3, off = (seg & 7) * 8;
        *(shortx8*)&Atl[row * 72 + off] =
            *(const shortx8*)&Atlg[h * 4096 + row * 64 + off];
    }
    if (tid < 64) vhs[tid] = vhg[h * 64 + tid];
    __syncthreads();

    // ---- phase B: qhat via MFMA; wave w -> tile (w&1), cn pair (w>>1) ------
    {
        const int t = w & 1, cnb = (w >> 1) * 2;
        shortx8 qa[2];
        #pragma unroll
        for (int kk = 0; kk < 2; ++kk)
            qa[kk] = *(shortx8*)&qstage[(t * 16 + ln) * 72 + kk * 32 + quad * 8];
        #pragma unroll
        for (int i = 0; i < 2; ++i) {
            int cn = cnb + i;
            floatx4 acc = {};
            #pragma unroll
            for (int kk = 0; kk < 2; ++kk) {
                shortx8 bfr = *(shortx8*)&Atl[(cn * 16 + ln) * 72 + kk * 32 + quad * 8];
                acc = __builtin_amdgcn_mfma_f32_16x16x32_bf16(qa[kk], bfr, acc, 0, 0, 0);
            }
            #pragma unroll
            for (int r = 0; r < 4; ++r)
                qh[(t * 16 + quad * 4 + r) * 72 + cn * 16 + ln] =
                    f2bf((acc[r] + vhs[cn * 16 + ln]) * QSCALE);
        }
    }
    __syncthreads();

    // ---- main loop: 8 steps of 64 keys, no barriers ------------------------
    shortx8 qf[2][2];
    #pragma unroll
    for (int t = 0; t < 2; ++t)
        #pragma unroll
        for (int kk = 0; kk < 2; ++kk)
            qf[t][kk] = *(shortx8*)&qh[(t * 16 + ln) * 72 + kk * 32 + quad * 8];

    // chunk bases: key-block b = cw*8 + i ; each block = 8 frags * 512 ushort
    const unsigned short* KbC = KbS + (size_t)cw * 8 * 4096 + lane * 8;
    const unsigned short* VTC = VTS + (size_t)cw * 8 * 4096 + lane * 8;

    shortx8 pk[8], pv[8];
    #pragma unroll
    for (int j = 0; j < 8; ++j)
        pk[j] = *(const shortx8*)&KbC[j * 512];

    floatx4 O0[4] = {}, O1[4] = {};
    float lacc0[4] = {}, lacc1[4] = {};

    for (int i = 0; i < 8; ++i) {
        // V frags for this step (issue first: latency cover across QK+exp)
        {
            const unsigned short* vb = VTC + (size_t)i * 4096;
            #pragma unroll
            for (int j = 0; j < 8; ++j)
                pv[j] = *(const shortx8*)&vb[j * 512];
        }
        // QK (both row-tiles)
        floatx4 S0[4], S1[4];
        #pragma unroll
        for (int cm = 0; cm < 4; ++cm) {
            floatx4 a0 = {}, a1 = {};
            a0 = __builtin_amdgcn_mfma_f32_16x16x32_bf16(qf[0][0], pk[cm * 2], a0, 0, 0, 0);
            a0 = __builtin_amdgcn_mfma_f32_16x16x32_bf16(qf[0][1], pk[cm * 2 + 1], a0, 0, 0, 0);
            a1 = __builtin_amdgcn_mfma_f32_16x16x32_bf16(qf[1][0], pk[cm * 2], a1, 0, 0, 0);
            a1 = __builtin_amdgcn_mfma_f32_16x16x32_bf16(qf[1][1], pk[cm * 2 + 1], a1, 0, 0, 0);
            S0[cm] = a0; S1[cm] = a1;
        }
        // K frags for s+1 (in-flight across exp + PV)
        if (i < 7) {
            const unsigned short* kb = KbC + (size_t)(i + 1) * 4096;
            #pragma unroll
            for (int j = 0; j < 8; ++j)
                pk[j] = *(const shortx8*)&kb[j * 512];
        }
        // exp2 + P (wave-private LDS, stride 76)
        #pragma unroll
        for (int cm = 0; cm < 4; ++cm) {
            #pragma unroll
            for (int r = 0; r < 4; ++r) {
                float p0 = __builtin_amdgcn_exp2f(S0[cm][r]); lacc0[r] += p0;
                Pw[(quad * 4 + r) * 76 + cm * 16 + ln] = f2bf(p0);
                float p1 = __builtin_amdgcn_exp2f(S1[cm][r]); lacc1[r] += p1;
                Pw[(16 + quad * 4 + r) * 76 + cm * 16 + ln] = f2bf(p1);
            }
        }
        // P frags (same wave wrote them: lgkmcnt ordering only, no barrier)
        shortx8 pf[2][2];
        #pragma unroll
        for (int t = 0; t < 2; ++t)
            #pragma unroll
            for (int kk = 0; kk < 2; ++kk)
                pf[t][kk] = *(shortx8*)&Pw[(t * 16 + ln) * 76 + kk * 32 + quad * 8];
        // PV
        #pragma unroll
        for (int cv = 0; cv < 4; ++cv) {
            O0[cv] = __builtin_amdgcn_mfma_f32_16x16x32_bf16(pf[0][0], pv[cv * 2], O0[cv], 0, 0, 0);
            O0[cv] = __builtin_amdgcn_mfma_f32_16x16x32_bf16(pf[0][1], pv[cv * 2 + 1], O0[cv], 0, 0, 0);
            O1[cv] = __builtin_amdgcn_mfma_f32_16x16x32_bf16(pf[1][0], pv[cv * 2], O1[cv], 0, 0, 0);
            O1[cv] = __builtin_amdgcn_mfma_f32_16x16x32_bf16(pf[1][1], pv[cv * 2 + 1], O1[cv], 0, 0, 0);
        }
    }

    // ---- epilogue: row-sums, LINV, per-lane O.LINV dot, quad-reduce --------
    float lr0[4], lr1[4];
    #pragma unroll
    for (int r = 0; r < 4; ++r) {
        float x0 = lacc0[r], x1 = lacc1[r];
        #pragma unroll
        for (int o = 1; o <= 8; o <<= 1) { x0 += __shfl_xor(x0, o); x1 += __shfl_xor(x1, o); }
        lr0[r] = x0; lr1[r] = x1;
    }
    __syncthreads();   // all waves done with Pw/qh -> overlay LSUM/LINV/Rred
    if (ln == 0) {
        #pragma unroll
        for (int r = 0; r < 4; ++r) {
            LSUM[w * 32 + quad * 4 + r] = lr0[r];
            LSUM[w * 32 + 16 + quad * 4 + r] = lr1[r];
        }
    }
    __syncthreads();
    if (tid < 32)
        LINV[tid] = 1.0f / (LSUM[tid] + LSUM[32 + tid] + LSUM[64 + tid] + LSUM[96 + tid]);
    __syncthreads();
    {
        float sacc[4];
        #pragma unroll
        for (int cv = 0; cv < 4; ++cv) {
            float s = 0.f;
            #pragma unroll
            for (int r = 0; r < 4; ++r) {
                s += O0[cv][r] * LINV[quad * 4 + r];
                s += O1[cv][r] * LINV[16 + quad * 4 + r];
            }
            s += __shfl_xor(s, 16);
            s += __shfl_xor(s, 32);
            sacc[cv] = s;
        }
        if (quad == 0) {
            #pragma unroll
            for (int cv = 0; cv < 4; ++cv)
                Rred[w * 64 + cv * 16 + ln] = sacc[cv];
        }
    }
    __syncthreads();
    if (tid < 64)
        atomicAdd(&r_ws[h * 64 + tid],
                  Rred[tid] + Rred[64 + tid] + Rred[128 + tid] + Rred[192 + tid]);
}

// =================== pool: pooled[d] = 2048*sum_h bv + sum_hv r*Wv ----------
__global__ __launch_bounds__(256) void pool_kernel(
    const float* __restrict__ Wv, const float* __restrict__ bv,
    const float* __restrict__ r_ws, float* __restrict__ pooled) {
    const int tid = threadIdx.x;
    const int d0 = blockIdx.x * 16;       // grid 64
    const int d = tid & 15, hh = tid >> 4;
    __shared__ float red[16][17];
    float acc = bv[hh * 1024 + d0 + d] * 2048.0f;
    const float* rv = r_ws + hh * 64;
    const float* wp = Wv + (size_t)hh * 64 * 1024 + d0 + d;
    #pragma unroll 8
    for (int v = 0; v < 64; ++v) acc += rv[v] * wp[(size_t)v * 1024];
    red[hh][d] = acc;
    __syncthreads();
    if (tid < 16) {
        float s = 0.f;
        #pragma unroll
        for (int g = 0; g < 16; ++g) s += red[g][tid];
        pooled[d0 + tid] = s;
    }
}

// =================== out: out[dp] = pooled . Wo[dp,:] + bo[dp] ---------------
__global__ __launch_bounds__(256) void out_kernel(
    const float* __restrict__ Wo, const float* __restrict__ bo,
    const float* __restrict__ pooled, float* __restrict__ out) {
    const int tid = threadIdx.x, w = tid >> 6, lane = tid & 63;
    const int dp = blockIdx.x * 4 + w;    // grid 256
    const float* wr = Wo + (size_t)dp * 1024 + lane * 16;
    const float* pp = pooled + lane * 16;
    float acc = 0.f;
    #pragma unroll
    for (int u = 0; u < 4; ++u) {
        float4 a = *(const float4*)&wr[u * 4];
        float4 p = *(const float4*)&pp[u * 4];
        acc += a.x * p.x + a.y * p.y + a.z * p.z + a.w * p.w;
    }
    #pragma unroll
    for (int o = 32; o > 0; o >>= 1) acc += __shfl_xor(acc, o);
    if (lane == 0) out[dp] = acc + bo[dp];
}

extern "C" void kernel_launch(void* const* d_in, const int* in_sizes, int n_in,
                              void* d_out, int out_size, void* d_ws, size_t ws_size,
                              hipStream_t stream) {
    const float* queries = (const float*)d_in[0];
    const float* keys    = (const float*)d_in[1];
    const float* values  = (const float*)d_in[2];
    const float* Wq      = (const float*)d_in[3];
    const float* bq      = (const float*)d_in[4];
    const float* Wk      = (const float*)d_in[5];
    // d_in[6] = bk: row-constant under softmax, unused
    const float* Wv      = (const float*)d_in[7];
    const float* bv      = (const float*)d_in[8];
    const float* Wo      = (const float*)d_in[9];
    const float* bo      = (const float*)d_in[10];
    float* out = (float*)d_out;

    float* Apart  = (float*)d_ws;                 // 128*4096 floats
    float* vhpart = Apart + 524288;               // 128*64
    float* r_ws   = vhpart + 8192;                // 1024
    float* pooled = r_ws + 1024;                  // 1024
    unsigned short* KbS = (unsigned short*)(pooled + 1024);  // 32*8*512
    unsigned short* VTS = KbS + 131072;                      // 32*8*512
    unsigned short* Atlg = VTS + 131072;                     // 16*64*64 bf16
    float* vhg = (float*)(Atlg + 65536);                     // 16*64
    // total ws: ~2.8 MB

    prep_kernel<<<176, 256, 0, stream>>>(Wq, Wk, bq, keys, values,
                                         Apart, vhpart, KbS, VTS, r_ws);
    reduceA_kernel<<<64, 256, 0, stream>>>(Apart, vhpart, Atlg, vhg);
    flash_kernel<<<dim3(64, 16), 256, 0, stream>>>(queries, Atlg, vhg,
                                                   KbS, VTS, r_ws);
    pool_kernel<<<64, 256, 0, stream>>>(Wv, bv, r_ws, pooled);
    out_kernel<<<256, 256, 0, stream>>>(Wo, bo, pooled, out);
}

// Round 7
// 132.568 us; speedup vs baseline: 1.5221x; 1.0079x over previous
//
#include <hip/hip_runtime.h>

// H=16, DK=DV=64, D=1024, N=M=2048.
// scores[h,n,m] = ((A_h^T q_n + vh_h) . k_m)/8 + row-consts (drop in softmax),
//   A_h[i][j] = sum_d Wq[h,i,d]*Wk[h,j,d],  vh_h[j] = sum_d Wk[h,j,d]*bq[h,d].
// pooled[d] = sum_h sum_v r_h[v]*Wv[h,v,d] + 2048*sum_h bv[h,d],
//   r_h[v] = sum_n softmax_row . V[:,v].   out = pooled @ Wo^T + bo.
// No max-tracking softmax: |s|max ~ 27 << 88 -> exp safe in fp32.
//
// v7: flash restructured for K/V REUSE. v6 counters: per CU-step the 16
// frag loads x 16 lines x 16 waves = ~33K TA line-transactions (13.7us of
// texture-pipe serialization), zero reuse within a block. Now: block =
// 128 q-rows x 1 head (8 waves), 32 steps of 64 keys; K/V tiles staged
// ONCE per step into double-buffered LDS, shared by all 8 waves -> TA
// traffic /4. One barrier/step (write next buf before barrier, read after).
// Fragment math identical to the verified v1 kernel (stride-72 LDS).

typedef __attribute__((ext_vector_type(4))) float floatx4;
typedef __attribute__((ext_vector_type(8))) short shortx8;

__device__ inline unsigned short f2bf(float f) {
    unsigned int u = __float_as_uint(f);
    u += 0x7FFFu + ((u >> 16) & 1u);   // RNE
    return (unsigned short)(u >> 16);
}
__device__ inline float bf2f(unsigned short s) {
    return __uint_as_float(((unsigned int)s) << 16);
}

// =================== prep: fused A-partials / K-cvt / V-transpose ============
// grid 176: blocks 0-127: (g,h) A-partial + vh-partial via MFMA (k-chunk 128)
//           blocks 128-143: K bf16 convert (linear) + r zero
//           blocks 144-175: V transpose -> VT bf16 (linear [64][2048])
__global__ __launch_bounds__(256) void prep_kernel(
    const float* __restrict__ Wq, const float* __restrict__ Wk,
    const float* __restrict__ bq, const float* __restrict__ keys,
    const float* __restrict__ values,
    float* __restrict__ Apart, float* __restrict__ vhpart,
    unsigned short* __restrict__ Kb, unsigned short* __restrict__ VT,
    float* __restrict__ r_ws) {
    const int tid = threadIdx.x;
    const int bx = blockIdx.x;
    __shared__ __align__(16) unsigned char sm[36352];
    if (bx < 128) {
        const int g = bx >> 4, h = bx & 15;
        const int c0 = g * 128;
        unsigned short* wq = (unsigned short*)sm;            // 64*136 ushort
        unsigned short* wk = (unsigned short*)(sm + 17408);  // 64*136 ushort
        float* bqs = (float*)(sm + 34816);                   // 128
        float* vred = (float*)(sm + 35328);                  // 4*64
        {
            int row = tid >> 2, cs = (tid & 3) * 32;
            const float* wqp = Wq + (size_t)(h * 64 + row) * 1024 + c0 + cs;
            const float* wkp = Wk + (size_t)(h * 64 + row) * 1024 + c0 + cs;
            #pragma unroll
            for (int u = 0; u < 8; ++u) {
                float4 a = *(const float4*)&wqp[u * 4];
                float4 b = *(const float4*)&wkp[u * 4];
                *(ushort4*)&wq[row * 136 + cs + u * 4] =
                    (ushort4){f2bf(a.x), f2bf(a.y), f2bf(a.z), f2bf(a.w)};
                *(ushort4*)&wk[row * 136 + cs + u * 4] =
                    (ushort4){f2bf(b.x), f2bf(b.y), f2bf(b.z), f2bf(b.w)};
            }
            if (tid < 128) bqs[tid] = bq[h * 1024 + c0 + tid];
        }
        __syncthreads();
        const int w = tid >> 6, lane = tid & 63;
        const int ln = lane & 15, quad = lane >> 4;
        {   // vh partial
            const int j = tid & 63, half = tid >> 6;
            float accv = 0.f;
            #pragma unroll
            for (int u = 0; u < 32; ++u)
                accv += bf2f(wk[j * 136 + half * 32 + u]) * bqs[half * 32 + u];
            vred[half * 64 + j] = accv;
        }
        // A-tile: wave w -> rows w*16..+15
        shortx8 af[4];
        #pragma unroll
        for (int kk = 0; kk < 4; ++kk)
            af[kk] = *(shortx8*)&wq[(w * 16 + ln) * 136 + kk * 32 + quad * 8];
        float* ap = Apart + (size_t)bx * 4096;
        #pragma unroll
        for (int cn = 0; cn < 4; ++cn) {
            floatx4 acc = {};
            #pragma unroll
            for (int kk = 0; kk < 4; ++kk) {
                shortx8 bf_ = *(shortx8*)&wk[(cn * 16 + ln) * 136 + kk * 32 + quad * 8];
                acc = __builtin_amdgcn_mfma_f32_16x16x32_bf16(af[kk], bf_, acc, 0, 0, 0);
            }
            #pragma unroll
            for (int r = 0; r < 4; ++r)
                ap[(w * 16 + quad * 4 + r) * 64 + cn * 16 + ln] = acc[r];
        }
        __syncthreads();
        if (tid < 64)
            vhpart[bx * 64 + tid] = vred[tid] + vred[64 + tid] +
                                    vred[128 + tid] + vred[192 + tid];
    } else if (bx < 144) {
        int bk = bx - 128;
        int base = (bk * 256 + tid) * 32;
        #pragma unroll
        for (int u = 0; u < 8; ++u) {
            float4 a = *(const float4*)&keys[base + u * 4];
            *(ushort4*)&Kb[base + u * 4] =
                (ushort4){f2bf(a.x), f2bf(a.y), f2bf(a.z), f2bf(a.w)};
        }
        if (tid < 64) r_ws[bk * 64 + tid] = 0.f;
    } else {
        int bb = bx - 144, m0 = bb * 64;
        unsigned short* vts = (unsigned short*)sm;   // 64*72 ushort
        #pragma unroll
        for (int it = 0; it < 4; ++it) {
            int gi = tid + it * 256;
            int m = gi >> 4, c4 = (gi & 15) * 4;
            float4 a = *(const float4*)&values[(size_t)(m0 + m) * 64 + c4];
            vts[(c4 + 0) * 72 + m] = f2bf(a.x);
            vts[(c4 + 1) * 72 + m] = f2bf(a.y);
            vts[(c4 + 2) * 72 + m] = f2bf(a.z);
            vts[(c4 + 3) * 72 + m] = f2bf(a.w);
        }
        __syncthreads();
        #pragma unroll
        for (int it = 0; it < 2; ++it) {
            int gi = tid + it * 256;
            int v = gi >> 3, seg = (gi & 7) * 8;
            *(shortx8*)&VT[v * 2048 + m0 + seg] = *(shortx8*)&vts[v * 72 + seg];
        }
    }
}

// =================== reduceA: sum 8 A-partials -> Atlg (A^T, bf16), vhg ======
__global__ __launch_bounds__(256) void reduceA_kernel(
    const float* __restrict__ Apart, const float* __restrict__ vhpart,
    unsigned short* __restrict__ Atlg, float* __restrict__ vhg) {
    const int tid = threadIdx.x;
    const int h = blockIdx.x >> 2, uq = blockIdx.x & 3;
    #pragma unroll
    for (int uu = 0; uu < 4; ++uu) {
        int e = (uq * 4 + uu) * 256 + tid;     // e = i*64 + j
        float s = 0.f;
        #pragma unroll
        for (int g = 0; g < 8; ++g)
            s += Apart[g * 65536 + h * 4096 + e];
        Atlg[h * 4096 + (e & 63) * 64 + (e >> 6)] = f2bf(s);   // A^T[j][i]
    }
    if (uq == 0 && tid < 64) {
        float s = 0.f;
        #pragma unroll
        for (int g = 0; g < 8; ++g) s += vhpart[(g * 16 + h) * 64 + tid];
        vhg[h * 64 + tid] = s;
    }
}

// =================== flash v7: grid (16 qtiles of 128 rows, 16 h) ============
// 512 threads = 8 waves; wave w owns rows n0+w*16..+15. 32 steps of 64 keys.
// Per step: K-tile (8KB) + V-tile (8KB) staged into dbuf LDS by all threads,
// consumed by all 8 waves (TA traffic /4 vs per-wave fragment loads).
// One barrier/step: compute reads buf[s&1]; staged regs written to buf[s&1^1]
// (whose readers finished at the PREVIOUS barrier); barrier publishes them.
#define QSCALE 0.18033688f   /* 0.125 * log2(e) */
__global__ __launch_bounds__(512, 2) void flash_kernel(
    const float* __restrict__ queries, const unsigned short* __restrict__ Atlg,
    const float* __restrict__ vhg, const unsigned short* __restrict__ Kb,
    const unsigned short* __restrict__ VT, float* __restrict__ r_ws) {
    const int h = blockIdx.y;
    const int n0 = blockIdx.x * 128;
    const int tid = threadIdx.x;
    const int w = tid >> 6, lane = tid & 63;
    const int ln = lane & 15, quad = lane >> 4;

    __shared__ __align__(16) unsigned char lds[73728];
    __shared__ float vhs[64];
    // main loop: Kbuf[2] @0/@9216 ; Vbuf[2] @18432/@27648 ; qh @36864 (18432B)
    //            Pw @55296 + w*2304 ([16][72] shorts per wave)
    // phase A/B: qstage @0 ([128][72]=18432B), Atl @18432 (9216B) -- both dead
    //            before K/V staging overwrites them (barrier-ordered).
    // epilogue:  Rred @0 (8*64 f32) after final barrier.
    unsigned short* Kbuf = (unsigned short*)lds;            // +b*4608 shorts
    unsigned short* Vbuf = (unsigned short*)(lds + 18432);  // +b*4608 shorts
    unsigned short* qh   = (unsigned short*)(lds + 36864);
    unsigned short* Pw   = (unsigned short*)(lds + 55296 + w * 2304);
    unsigned short* qstage = (unsigned short*)lds;
    unsigned short* Atl  = (unsigned short*)(lds + 18432);
    float* Rred = (float*)lds;

    // ---- phase A: stage queries (bf16) [128][72], Atl (8KB coalesced), vhs -
    {
        int row = tid >> 2, c16 = (tid & 3) * 16;
        const float* qp = queries + (size_t)(n0 + row) * 64 + c16;
        #pragma unroll
        for (int u = 0; u < 4; ++u) {
            float4 a = *(const float4*)&qp[u * 4];
            *(ushort4*)&qstage[row * 72 + c16 + u * 4] =
                (ushort4){f2bf(a.x), f2bf(a.y), f2bf(a.z), f2bf(a.w)};
        }
    }
    {
        int row = tid >> 3, off = (tid & 7) * 8;
        *(shortx8*)&Atl[row * 72 + off] =
            *(const shortx8*)&Atlg[h * 4096 + row * 64 + off];
    }
    if (tid < 64) vhs[tid] = vhg[h * 64 + tid];
    __syncthreads();

    // ---- phase B: qhat = (q.A^T + vh)*scale; wave w -> rows w*16..+15 ------
    {
        shortx8 qa[2];
        #pragma unroll
        for (int kk = 0; kk < 2; ++kk)
            qa[kk] = *(shortx8*)&qstage[(w * 16 + ln) * 72 + kk * 32 + quad * 8];
        #pragma unroll
        for (int cn = 0; cn < 4; ++cn) {
            floatx4 acc = {};
            #pragma unroll
            for (int kk = 0; kk < 2; ++kk) {
                shortx8 bfr = *(shortx8*)&Atl[(cn * 16 + ln) * 72 + kk * 32 + quad * 8];
                acc = __builtin_amdgcn_mfma_f32_16x16x32_bf16(qa[kk], bfr, acc, 0, 0, 0);
            }
            #pragma unroll
            for (int r = 0; r < 4; ++r)
                qh[(w * 16 + quad * 4 + r) * 72 + cn * 16 + ln] =
                    f2bf((acc[r] + vhs[cn * 16 + ln]) * QSCALE);
        }
    }
    __syncthreads();   // qstage/Atl dead -> staging may overwrite lds[0..36863]

    // ---- prologue: stage step-0 K/V tiles ----------------------------------
    const int srow = tid >> 3, scol = (tid & 7) * 8;   // 64 rows x 8 segs
    {
        shortx8 kr = *(const shortx8*)&Kb[(size_t)srow * 64 + scol];
        shortx8 vr = *(const shortx8*)&VT[srow * 2048 + scol];
        *(shortx8*)&Kbuf[srow * 72 + scol] = kr;
        *(shortx8*)&Vbuf[srow * 72 + scol] = vr;
    }
    // qf: own wave wrote its qh rows (lgkm-ordered); read A-frag
    shortx8 qf[2];
    #pragma unroll
    for (int kk = 0; kk < 2; ++kk)
        qf[kk] = *(shortx8*)&qh[(w * 16 + ln) * 72 + kk * 32 + quad * 8];
    __syncthreads();

    // ---- main loop: 32 steps of 64 keys, 1 barrier/step --------------------
    floatx4 O[4] = {};
    float lacc[4] = {};
    for (int s = 0; s < 32; ++s) {
        const int b = s & 1;
        const unsigned short* kb = Kbuf + b * 4608;
        const unsigned short* vb = Vbuf + b * 4608;
        // issue next-step staging loads (consumed at step end: latency hidden)
        shortx8 krn, vrn;
        if (s < 31) {
            int m0n = (s + 1) * 64;
            krn = *(const shortx8*)&Kb[(size_t)(m0n + srow) * 64 + scol];
            vrn = *(const shortx8*)&VT[srow * 2048 + m0n + scol];
        }
        // QK: S[cm] = qhat_tile . K_tile^T
        floatx4 S[4];
        #pragma unroll
        for (int cm = 0; cm < 4; ++cm) {
            floatx4 acc = {};
            #pragma unroll
            for (int kk = 0; kk < 2; ++kk) {
                shortx8 kf = *(const shortx8*)&kb[(cm * 16 + ln) * 72 + kk * 32 + quad * 8];
                acc = __builtin_amdgcn_mfma_f32_16x16x32_bf16(qf[kk], kf, acc, 0, 0, 0);
            }
            S[cm] = acc;
        }
        // exp2 + P (wave-private LDS)
        #pragma unroll
        for (int cm = 0; cm < 4; ++cm) {
            #pragma unroll
            for (int r = 0; r < 4; ++r) {
                float p = __builtin_amdgcn_exp2f(S[cm][r]);
                lacc[r] += p;
                Pw[(quad * 4 + r) * 72 + cm * 16 + ln] = f2bf(p);
            }
        }
        // P frags (same wave wrote them: lgkm ordering, no barrier)
        shortx8 pf[2];
        #pragma unroll
        for (int kk = 0; kk < 2; ++kk)
            pf[kk] = *(shortx8*)&Pw[ln * 72 + kk * 32 + quad * 8];
        // PV
        #pragma unroll
        for (int cv = 0; cv < 4; ++cv) {
            shortx8 v0 = *(const shortx8*)&vb[(cv * 16 + ln) * 72 + quad * 8];
            shortx8 v1 = *(const shortx8*)&vb[(cv * 16 + ln) * 72 + 32 + quad * 8];
            O[cv] = __builtin_amdgcn_mfma_f32_16x16x32_bf16(pf[0], v0, O[cv], 0, 0, 0);
            O[cv] = __builtin_amdgcn_mfma_f32_16x16x32_bf16(pf[1], v1, O[cv], 0, 0, 0);
        }
        // publish next-step tiles into the other buffer (its readers finished
        // at the previous barrier), then barrier releases everyone into s+1
        if (s < 31) {
            unsigned short* kbn = Kbuf + (b ^ 1) * 4608;
            unsigned short* vbn = Vbuf + (b ^ 1) * 4608;
            *(shortx8*)&kbn[srow * 72 + scol] = krn;
            *(shortx8*)&vbn[srow * 72 + scol] = vrn;
        }
        __syncthreads();
    }

    // ---- epilogue: wave-local row sums + normalize + r accumulate ----------
    float linv[4];
    #pragma unroll
    for (int r = 0; r < 4; ++r) {
        float x = lacc[r];
        #pragma unroll
        for (int o = 1; o <= 8; o <<= 1) x += __shfl_xor(x, o);
        linv[r] = 1.0f / x;   // row w*16+quad*4+r full sum (all 2048 keys)
    }
    float sacc[4];
    #pragma unroll
    for (int cv = 0; cv < 4; ++cv) {
        float s = 0.f;
        #pragma unroll
        for (int r = 0; r < 4; ++r) s += O[cv][r] * linv[r];
        s += __shfl_xor(s, 16);
        s += __shfl_xor(s, 32);
        sacc[cv] = s;          // sum over the wave's 16 rows, col cv*16+ln
    }
    __syncthreads();           // K/V/P buffers dead -> Rred overlay
    if (quad == 0) {
        #pragma unroll
        for (int cv = 0; cv < 4; ++cv)
            Rred[w * 64 + cv * 16 + ln] = sacc[cv];
    }
    __syncthreads();
    if (tid < 64) {
        float s = 0.f;
        #pragma unroll
        for (int g = 0; g < 8; ++g) s += Rred[g * 64 + tid];
        atomicAdd(&r_ws[h * 64 + tid], s);
    }
}

// =================== pool: pooled[d] = 2048*sum_h bv + sum_hv r*Wv ----------
__global__ __launch_bounds__(256) void pool_kernel(
    const float* __restrict__ Wv, const float* __restrict__ bv,
    const float* __restrict__ r_ws, float* __restrict__ pooled) {
    const int tid = threadIdx.x;
    const int d0 = blockIdx.x * 16;       // grid 64
    const int d = tid & 15, hh = tid >> 4;
    __shared__ float red[16][17];
    float acc = bv[hh * 1024 + d0 + d] * 2048.0f;
    const float* rv = r_ws + hh * 64;
    const float* wp = Wv + (size_t)hh * 64 * 1024 + d0 + d;
    #pragma unroll 8
    for (int v = 0; v < 64; ++v) acc += rv[v] * wp[(size_t)v * 1024];
    red[hh][d] = acc;
    __syncthreads();
    if (tid < 16) {
        float s = 0.f;
        #pragma unroll
        for (int g = 0; g < 16; ++g) s += red[g][tid];
        pooled[d0 + tid] = s;
    }
}

// =================== out: out[dp] = pooled . Wo[dp,:] + bo[dp] ---------------
__global__ __launch_bounds__(256) void out_kernel(
    const float* __restrict__ Wo, const float* __restrict__ bo,
    const float* __restrict__ pooled, float* __restrict__ out) {
    const int tid = threadIdx.x, w = tid >> 6, lane = tid & 63;
    const int dp = blockIdx.x * 4 + w;    // grid 256
    const float* wr = Wo + (size_t)dp * 1024 + lane * 16;
    const float* pp = pooled + lane * 16;
    float acc = 0.f;
    #pragma unroll
    for (int u = 0; u < 4; ++u) {
        float4 a = *(const float4*)&wr[u * 4];
        float4 p = *(const float4*)&pp[u * 4];
        acc += a.x * p.x + a.y * p.y + a.z * p.z + a.w * p.w;
    }
    #pragma unroll
    for (int o = 32; o > 0; o >>= 1) acc += __shfl_xor(acc, o);
    if (lane == 0) out[dp] = acc + bo[dp];
}

extern "C" void kernel_launch(void* const* d_in, const int* in_sizes, int n_in,
                              void* d_out, int out_size, void* d_ws, size_t ws_size,
                              hipStream_t stream) {
    const float* queries = (const float*)d_in[0];
    const float* keys    = (const float*)d_in[1];
    const float* values  = (const float*)d_in[2];
    const float* Wq      = (const float*)d_in[3];
    const float* bq      = (const float*)d_in[4];
    const float* Wk      = (const float*)d_in[5];
    // d_in[6] = bk: row-constant under softmax, unused
    const float* Wv      = (const float*)d_in[7];
    const float* bv      = (const float*)d_in[8];
    const float* Wo      = (const float*)d_in[9];
    const float* bo      = (const float*)d_in[10];
    float* out = (float*)d_out;

    float* Apart  = (float*)d_ws;                 // 128*4096 floats
    float* vhpart = Apart + 524288;               // 128*64
    float* r_ws   = vhpart + 8192;                // 1024
    float* pooled = r_ws + 1024;                  // 1024
    unsigned short* Kb = (unsigned short*)(pooled + 1024);  // 2048*64 bf16
    unsigned short* VT = Kb + 131072;                       // 64*2048 bf16
    unsigned short* Atlg = VT + 131072;                     // 16*64*64 bf16
    float* vhg = (float*)(Atlg + 65536);                    // 16*64
    // total ws: ~2.8 MB

    prep_kernel<<<176, 256, 0, stream>>>(Wq, Wk, bq, keys, values,
                                         Apart, vhpart, Kb, VT, r_ws);
    reduceA_kernel<<<64, 256, 0, stream>>>(Apart, vhpart, Atlg, vhg);
    flash_kernel<<<dim3(16, 16), 512, 0, stream>>>(queries, Atlg, vhg,
                                                   Kb, VT, r_ws);
    pool_kernel<<<64, 256, 0, stream>>>(Wv, bv, r_ws, pooled);
    out_kernel<<<256, 256, 0, stream>>>(Wo, bo, pooled, out);
}